// Round 1
// baseline (55966.083 us; speedup 1.0000x reference)
//
#include <hip/hip_runtime.h>

#define HH 383
#define WW 383
#define CINC 64
#define COUTC 128
#define HO 191
#define WO 191

// ---------------- zero d_out ----------------
__global__ void zero_f4(float4* __restrict__ p, long n4) {
    long i = blockIdx.x * (long)blockDim.x + threadIdx.x;
    long stride = (long)gridDim.x * blockDim.x;
    float4 z = make_float4(0.f, 0.f, 0.f, 0.f);
    for (; i < n4; i += stride) p[i] = z;
}

// ---------------- scatter features -> dense NHWC (in d_out) ----------------
__global__ void scatter_feats(const float4* __restrict__ feats,
                              const int* __restrict__ coors,
                              float4* __restrict__ dense, int npts) {
    int t = blockIdx.x * blockDim.x + threadIdx.x;
    int total = npts * 16;  // 16 float4 per point (64 ch)
    if (t >= total) return;
    int p = t >> 4, q = t & 15;
    int b = coors[3 * p], y = coors[3 * p + 1], x = coors[3 * p + 2];
    dense[(((long)b * HH + y) * WW + x) * 16 + q] = feats[t];
}

// ---------------- conv1: 3x3 stride-2 VALID, dense NHWC -> mid NHWC ----------------
// block: 256 threads. Each block: one (b,i) row, 16 j's, 128 couts.
// thread: co = tid&127, jhalf = tid>>7 -> 8 j outputs each.
__global__ __launch_bounds__(256) void conv1_kern(const float4* __restrict__ dense4,
                                                  const float* __restrict__ W1,
                                                  float* __restrict__ mid) {
    __shared__ float ds[3 * 33 * 64];  // rows 2i+ky, x in [2*j0, 2*j0+33), all ci
    const int j0 = blockIdx.x * 16;
    const int i = blockIdx.y;
    const int b = blockIdx.z;
    const int tid = threadIdx.x;

    // stage dense slab into LDS (zero-fill out-of-range x)
    for (int t = tid; t < 3 * 33 * 16; t += 256) {
        int ky = t / (33 * 16);
        int rem = t - ky * (33 * 16);
        int xx = rem >> 4;
        int c4 = rem & 15;
        int gx = 2 * j0 + xx;
        float4 v = make_float4(0.f, 0.f, 0.f, 0.f);
        if (gx < WW) v = dense4[(((long)b * HH + (2 * i + ky)) * WW + gx) * 16 + c4];
        *(float4*)&ds[(ky * 33 + xx) * 64 + c4 * 4] = v;
    }
    __syncthreads();

    const int co = tid & 127;
    const int jhalf = tid >> 7;
    const int xbase = jhalf * 16;  // = 2*(jhalf*8)
    float acc[8] = {0.f, 0.f, 0.f, 0.f, 0.f, 0.f, 0.f, 0.f};
    const float* w1c = W1 + co;

    #pragma unroll
    for (int tap = 0; tap < 9; ++tap) {
        const int ky = tap / 3;
        const int kx = tap - ky * 3;
        const float* wp = w1c + tap * 64 * 128;
        const float* dbase = ds + (ky * 33 + xbase + kx) * 64;
        for (int c4 = 0; c4 < 16; ++c4) {
            float w0 = wp[(c4 * 4 + 0) * 128];
            float w1v = wp[(c4 * 4 + 1) * 128];
            float w2v = wp[(c4 * 4 + 2) * 128];
            float w3v = wp[(c4 * 4 + 3) * 128];
            #pragma unroll
            for (int r = 0; r < 8; ++r) {
                const float4 d = *(const float4*)&dbase[r * 128 + c4 * 4];
                acc[r] = fmaf(d.x, w0, acc[r]);
                acc[r] = fmaf(d.y, w1v, acc[r]);
                acc[r] = fmaf(d.z, w2v, acc[r]);
                acc[r] = fmaf(d.w, w3v, acc[r]);
            }
        }
    }

    #pragma unroll
    for (int r = 0; r < 8; ++r) {
        int j = j0 + jhalf * 8 + r;
        if (j < WO) mid[(((long)b * HO + i) * WO + j) * COUTC + co] = acc[r];
    }
}

// ---------------- conv2 (transposed conv) evaluated only at active points ----------------
// up[y,x,c] = sum over ky,kx with (y+ky) even, (x+kx) even, i=(y+ky-2)/2 in [0,191),
//             j=(x+kx-2)/2 in [0,191):  mid[b,i,j,m] * W2[ky,kx,m,c]
// one wave (64 lanes = 64 output channels) per point.
__global__ __launch_bounds__(256) void conv2_scatter(const float* __restrict__ mid,
                                                     const float* __restrict__ W2,
                                                     const int* __restrict__ coors,
                                                     float* __restrict__ out, int npts) {
    int p = blockIdx.x * 4 + (threadIdx.x >> 6);
    if (p >= npts) return;
    int c = threadIdx.x & 63;
    int b = coors[3 * p], y = coors[3 * p + 1], x = coors[3 * p + 2];

    int ilist[2], kyl[2], ni = 0;
    if (y & 1) {
        ilist[0] = y >> 1; kyl[0] = 1; ni = 1;   // (y-1)/2 for odd y
    } else {
        if (y >= 2)   { ilist[ni] = (y >> 1) - 1; kyl[ni] = 0; ni++; }
        if (y <= 381) { ilist[ni] = y >> 1;       kyl[ni] = 2; ni++; }
    }
    int jlist[2], kxl[2], nj = 0;
    if (x & 1) {
        jlist[0] = x >> 1; kxl[0] = 1; nj = 1;
    } else {
        if (x >= 2)   { jlist[nj] = (x >> 1) - 1; kxl[nj] = 0; nj++; }
        if (x <= 381) { jlist[nj] = x >> 1;       kxl[nj] = 2; nj++; }
    }

    float acc = 0.f;
    for (int a = 0; a < ni; ++a) {
        for (int e = 0; e < nj; ++e) {
            const float* mp = mid + (((long)b * HO + ilist[a]) * WO + jlist[e]) * COUTC;
            const float* wp = W2 + ((kyl[a] * 3 + kxl[e]) * COUTC) * CINC + c;
            #pragma unroll
            for (int m4 = 0; m4 < 32; ++m4) {
                const float4 mv = *(const float4*)(mp + m4 * 4);
                acc = fmaf(mv.x, wp[(m4 * 4 + 0) * CINC], acc);
                acc = fmaf(mv.y, wp[(m4 * 4 + 1) * CINC], acc);
                acc = fmaf(mv.z, wp[(m4 * 4 + 2) * CINC], acc);
                acc = fmaf(mv.w, wp[(m4 * 4 + 3) * CINC], acc);
            }
        }
    }
    out[(((long)b * CINC + c) * HH + y) * WW + x] = acc;
}

extern "C" void kernel_launch(void* const* d_in, const int* in_sizes, int n_in,
                              void* d_out, int out_size, void* d_ws, size_t ws_size,
                              hipStream_t stream) {
    const float* feats = (const float*)d_in[0];
    const int* coors = (const int*)d_in[1];
    const float* W1 = (const float*)d_in[3];
    const float* W2 = (const float*)d_in[4];
    float* out = (float*)d_out;
    float* mid = (float*)d_ws;  // 4*191*191*128 floats = 74.7 MB
    int npts = in_sizes[1] / 3;

    long n4 = (long)out_size / 4;  // d_out as float4 count

    // 1) zero d_out, scatter features into it as dense NHWC
    zero_f4<<<2048, 256, 0, stream>>>((float4*)d_out, n4);
    int sthreads = npts * 16;
    scatter_feats<<<(sthreads + 255) / 256, 256, 0, stream>>>(
        (const float4*)feats, coors, (float4*)d_out, npts);

    // 2) conv1: dense (in d_out) -> mid (in d_ws)
    conv1_kern<<<dim3(12, HO, 4), 256, 0, stream>>>((const float4*)d_out, W1, mid);

    // 3) re-zero d_out, then masked transposed-conv scatter into NCHW output
    zero_f4<<<2048, 256, 0, stream>>>((float4*)d_out, n4);
    conv2_scatter<<<(npts + 3) / 4, 256, 0, stream>>>(mid, W2, coors, out, npts);
}

// Round 2
// 836.097 us; speedup vs baseline: 66.9373x; 66.9373x over previous
//
#include <hip/hip_runtime.h>

#define HH 383
#define WW 383
#define CINC 64
#define COUTC 128
#define HO 191
#define WO 191

// conv1 tiling
#define NI 8            // output rows per block
#define NJ 16           // output cols per block
#define ROW_STRIDE 536  // 33*16 + 8 pad (floats) -> 2-way-max bank aliasing
#define W_STRIDE 17     // per-cout stride in weight LDS (conflict-free for co=tx+16u)

// ---------------- zero d_out ----------------
__global__ void zero_f4(float4* __restrict__ p, long n4) {
    long i = blockIdx.x * (long)blockDim.x + threadIdx.x;
    long stride = (long)gridDim.x * blockDim.x;
    float4 z = make_float4(0.f, 0.f, 0.f, 0.f);
    for (; i < n4; i += stride) p[i] = z;
}

// ---------------- scatter features -> dense NHWC (in d_out) ----------------
__global__ void scatter_feats(const float4* __restrict__ feats,
                              const int* __restrict__ coors,
                              float4* __restrict__ dense, int npts) {
    int t = blockIdx.x * blockDim.x + threadIdx.x;
    int total = npts * 16;  // 16 float4 per point (64 ch)
    if (t >= total) return;
    int p = t >> 4, q = t & 15;
    int b = coors[3 * p], y = coors[3 * p + 1], x = coors[3 * p + 2];
    dense[(((long)b * HH + y) * WW + x) * 16 + q] = feats[t];
}

// ---------------- conv1: 3x3 stride-2 VALID, register-tiled implicit GEMM ----------------
// block: 256 threads = 4 waves. tile: 8 i x 16 j x 128 co.
// thread: tx=tid&15 -> couts {tx+16u, u=0..7}; ty=tid>>4 -> i=i0+(ty&7), j=j0+(ty>>3)*8+{0..7}.
// K blocked: cc = 4 chunks of 16 ci; per (cc,tap): weights (16ci x 128co) in LDS.
__global__ __launch_bounds__(256, 3) void conv1_kern(const float4* __restrict__ dense4,
                                                     const float* __restrict__ W1,
                                                     float* __restrict__ mid) {
    __shared__ float ds[17 * ROW_STRIDE];    // 9112 floats: 17 rows x 33 x x 16 ci (+pad)
    __shared__ float wsm[COUTC * W_STRIDE];  // 2176 floats: 128 co x 16 ci (+pad)

    const int j0 = blockIdx.x * NJ;
    const int i0 = blockIdx.y * NI;
    const int b  = blockIdx.z;
    const int tid = threadIdx.x;
    const int tx = tid & 15;
    const int ty = tid >> 4;
    const int il = ty & 7;   // local output row
    const int jh = ty >> 3;  // j half (0/1): j = j0 + jh*8 + r

    float acc[8][8];
    #pragma unroll
    for (int u = 0; u < 8; ++u)
        #pragma unroll
        for (int r = 0; r < 8; ++r) acc[u][r] = 0.f;

    for (int cc = 0; cc < 4; ++cc) {
        __syncthreads();  // previous-iteration ds readers done
        // stage data slab: rows 2*i0..2*i0+16, x 2*j0..2*j0+32, ci chunk cc (16 ch = 4 float4)
        for (int t = tid; t < 17 * 33 * 4; t += 256) {
            int rr  = t / 132;
            int rem = t - rr * 132;
            int xx  = rem >> 2;
            int c4  = rem & 3;
            int gr = 2 * i0 + rr;
            int gx = 2 * j0 + xx;
            float4 v = make_float4(0.f, 0.f, 0.f, 0.f);
            if (gr < HH && gx < WW)
                v = dense4[(((long)b * HH + gr) * WW + gx) * 16 + cc * 4 + c4];
            *(float4*)&ds[rr * ROW_STRIDE + xx * 16 + c4 * 4] = v;
        }

        for (int tap = 0; tap < 9; ++tap) {
            __syncthreads();  // previous FMA readers of wsm (and ds stage, tap 0) done
            // stage weights for (tap, cc): W1[tap][cc*16+ci_l][co] -> wsm[co][ci_l]
            for (int t = tid; t < 2048; t += 256) {
                int ci_l = t >> 7;
                int co   = t & 127;
                wsm[co * W_STRIDE + ci_l] = W1[(tap * 64 + cc * 16 + ci_l) * 128 + co];
            }
            __syncthreads();

            const int ky = tap / 3, kx = tap - ky * 3;
            const int drow  = (2 * il + ky) * ROW_STRIDE;
            const int dcol0 = (jh * 16 + kx) * 16;
            const int wbase = tx * W_STRIDE;

            #pragma unroll 1
            for (int c4 = 0; c4 < 4; ++c4) {
                float4 wv[8], dv[8];
                #pragma unroll
                for (int u = 0; u < 8; ++u)
                    wv[u] = *(const float4*)&wsm[wbase + u * (16 * W_STRIDE) + c4 * 4];
                #pragma unroll
                for (int r = 0; r < 8; ++r)
                    dv[r] = *(const float4*)&ds[drow + dcol0 + r * 32 + c4 * 4];
                #pragma unroll
                for (int u = 0; u < 8; ++u)
                    #pragma unroll
                    for (int r = 0; r < 8; ++r) {
                        acc[u][r] = fmaf(dv[r].x, wv[u].x, acc[u][r]);
                        acc[u][r] = fmaf(dv[r].y, wv[u].y, acc[u][r]);
                        acc[u][r] = fmaf(dv[r].z, wv[u].z, acc[u][r]);
                        acc[u][r] = fmaf(dv[r].w, wv[u].w, acc[u][r]);
                    }
            }
        }
    }

    // epilogue: mid[b, i, j, co] NHWC
    const int i = i0 + il;
    if (i < HO) {
        #pragma unroll
        for (int r = 0; r < 8; ++r) {
            int j = j0 + jh * 8 + r;
            if (j < WO) {
                long base = (((long)b * HO + i) * WO + j) * COUTC;
                #pragma unroll
                for (int u = 0; u < 8; ++u) mid[base + tx + 16 * u] = acc[u][r];
            }
        }
    }
}

// ---------------- conv2 (transposed conv) evaluated only at active points ----------------
__global__ __launch_bounds__(256) void conv2_scatter(const float* __restrict__ mid,
                                                     const float* __restrict__ W2,
                                                     const int* __restrict__ coors,
                                                     float* __restrict__ out, int npts) {
    int p = blockIdx.x * 4 + (threadIdx.x >> 6);
    if (p >= npts) return;
    int c = threadIdx.x & 63;
    int b = coors[3 * p], y = coors[3 * p + 1], x = coors[3 * p + 2];

    int ilist[2], kyl[2], ni = 0;
    if (y & 1) {
        ilist[0] = y >> 1; kyl[0] = 1; ni = 1;
    } else {
        if (y >= 2)   { ilist[ni] = (y >> 1) - 1; kyl[ni] = 0; ni++; }
        if (y <= 381) { ilist[ni] = y >> 1;       kyl[ni] = 2; ni++; }
    }
    int jlist[2], kxl[2], nj = 0;
    if (x & 1) {
        jlist[0] = x >> 1; kxl[0] = 1; nj = 1;
    } else {
        if (x >= 2)   { jlist[nj] = (x >> 1) - 1; kxl[nj] = 0; nj++; }
        if (x <= 381) { jlist[nj] = x >> 1;       kxl[nj] = 2; nj++; }
    }

    float acc = 0.f;
    for (int a = 0; a < ni; ++a) {
        for (int e = 0; e < nj; ++e) {
            const float* mp = mid + (((long)b * HO + ilist[a]) * WO + jlist[e]) * COUTC;
            const float* wp = W2 + ((kyl[a] * 3 + kxl[e]) * COUTC) * CINC + c;
            #pragma unroll
            for (int m4 = 0; m4 < 32; ++m4) {
                const float4 mv = *(const float4*)(mp + m4 * 4);
                acc = fmaf(mv.x, wp[(m4 * 4 + 0) * CINC], acc);
                acc = fmaf(mv.y, wp[(m4 * 4 + 1) * CINC], acc);
                acc = fmaf(mv.z, wp[(m4 * 4 + 2) * CINC], acc);
                acc = fmaf(mv.w, wp[(m4 * 4 + 3) * CINC], acc);
            }
        }
    }
    out[(((long)b * CINC + c) * HH + y) * WW + x] = acc;
}

extern "C" void kernel_launch(void* const* d_in, const int* in_sizes, int n_in,
                              void* d_out, int out_size, void* d_ws, size_t ws_size,
                              hipStream_t stream) {
    const float* feats = (const float*)d_in[0];
    const int* coors = (const int*)d_in[1];
    const float* W1 = (const float*)d_in[3];
    const float* W2 = (const float*)d_in[4];
    float* out = (float*)d_out;
    float* mid = (float*)d_ws;  // 4*191*191*128 floats = 74.7 MB
    int npts = in_sizes[1] / 3;

    long n4 = (long)out_size / 4;

    // 1) zero d_out, scatter features into it as dense NHWC
    zero_f4<<<2048, 256, 0, stream>>>((float4*)d_out, n4);
    int sthreads = npts * 16;
    scatter_feats<<<(sthreads + 255) / 256, 256, 0, stream>>>(
        (const float4*)feats, coors, (float4*)d_out, npts);

    // 2) conv1: dense (in d_out) -> mid (in d_ws)
    conv1_kern<<<dim3(12, 24, 4), 256, 0, stream>>>((const float4*)d_out, W1, mid);

    // 3) re-zero d_out, then masked transposed-conv scatter into NCHW output
    zero_f4<<<2048, 256, 0, stream>>>((float4*)d_out, n4);
    conv2_scatter<<<(npts + 3) / 4, 256, 0, stream>>>(mid, W2, coors, out, npts);
}